// Round 3
// baseline (188.764 us; speedup 1.0000x reference)
//
#include <hip/hip_runtime.h>

// VolSDF volume rendering: per-ray Laplace-CDF density -> transmittance scan
// -> weighted color aggregation. One 64-lane wave per ray, 2 points per lane.
//
// NOTE: lane 63's sentinel segment (density * FAR_DELTA ~ 1e11) must be kept
// OUT of the prefix scan: f32 ulp at 1e11 is ~8192, so excl = incl - s
// cancels catastrophically (excl -> 0, spurious weight ~1). dd[127] is never
// part of any transmittance prefix in the reference either.

#define ALPHA_C    10.0f
#define INV_BETA   20.0f      // 1 / 0.05
#define FAR_DELTA  1.0e10f
#define N_PTS      128

__device__ __forceinline__ float sdf_density(float dist) {
    float sd = -dist;
    // Laplace CDF: sd<=0 -> 0.5*exp(sd/beta); else 1 - 0.5*exp(-sd/beta)
    float e  = __expf(-fabsf(sd) * INV_BETA);
    return (sd <= 0.0f) ? (ALPHA_C * 0.5f * e)
                        : (ALPHA_C * (1.0f - 0.5f * e));
}

__global__ __launch_bounds__(256) void volsdf_render_kernel(
    const float* __restrict__ distance,
    const float* __restrict__ color,
    const float* __restrict__ depth,
    float* __restrict__ out,
    int n_rays)
{
    const int wave = (int)((blockIdx.x * blockDim.x + threadIdx.x) >> 6);
    const int lane = (int)(threadIdx.x & 63);
    if (wave >= n_rays) return;
    const int ray = wave;

    // ---- loads: lane l owns points p0=2l, p1=2l+1 (all coalesced) ----
    const float2 d2 = ((const float2*)(distance + (size_t)ray * N_PTS))[lane];
    const float2 z2 = ((const float2*)(depth    + (size_t)ray * N_PTS))[lane];
    const float2* c2 = (const float2*)(color + (size_t)ray * N_PTS * 3);
    const float2 ca = c2[lane * 3 + 0];  // p0.r, p0.g
    const float2 cb = c2[lane * 3 + 1];  // p0.b, p1.r
    const float2 cc = c2[lane * 3 + 2];  // p1.g, p1.b

    // ---- deltas ----
    float z_next  = __shfl_down(z2.x, 1, 64);            // depth[2l+2]
    float delta0  = z2.y - z2.x;
    float delta1  = (lane == 63) ? FAR_DELTA : (z_next - z2.y);

    // ---- optical thickness per segment ----
    float dd0 = sdf_density(d2.x) * delta0;
    float dd1 = sdf_density(d2.y) * delta1;

    // ---- exclusive prefix sum of dd across the wave (pair-sum scan) ----
    // Lane 63's dd1 (the 1e11 sentinel) is excluded: it belongs to no prefix,
    // and including it destroys the scan's precision (see NOTE above).
    float s = dd0 + ((lane == 63) ? 0.0f : dd1);
    float incl = s;
    #pragma unroll
    for (int off = 1; off < 64; off <<= 1) {
        float v = __shfl_up(incl, off, 64);
        if (lane >= off) incl += v;
    }
    float excl = incl - s;               // sum of dd_j for j < 2l

    // ---- transmittance & weights ----
    float T0 = __expf(-excl);
    float T1 = __expf(-(excl + dd0));
    float w0 = T0 * (1.0f - __expf(-dd0));
    float w1 = T1 * (1.0f - __expf(-dd1));   // lane 63: exp(-~1e11) == 0 -> w1 = T1

    // ---- weighted color partials ----
    float r = w0 * ca.x + w1 * cb.y;
    float g = w0 * ca.y + w1 * cc.x;
    float b = w0 * cb.x + w1 * cc.y;

    // ---- wave tree reduction ----
    #pragma unroll
    for (int off = 32; off >= 1; off >>= 1) {
        r += __shfl_down(r, off, 64);
        g += __shfl_down(g, off, 64);
        b += __shfl_down(b, off, 64);
    }

    if (lane == 0) {
        float* o = out + (size_t)ray * 3;
        o[0] = r;
        o[1] = g;
        o[2] = b;
    }
}

extern "C" void kernel_launch(void* const* d_in, const int* in_sizes, int n_in,
                              void* d_out, int out_size, void* d_ws, size_t ws_size,
                              hipStream_t stream) {
    const float* distance = (const float*)d_in[0];
    const float* color    = (const float*)d_in[1];
    const float* depth    = (const float*)d_in[2];
    float* out = (float*)d_out;

    const int n_rays = in_sizes[0] / N_PTS;          // 65536
    const int waves_per_block = 4;                   // 256 threads
    dim3 block(256);
    dim3 grid((n_rays + waves_per_block - 1) / waves_per_block);
    volsdf_render_kernel<<<grid, block, 0, stream>>>(distance, color, depth, out, n_rays);
}